// Round 8
// baseline (311.132 us; speedup 1.0000x reference)
//
#include <hip/hip_runtime.h>
#include <hip/hip_bf16.h>
#include <math.h>

// ---------------- problem constants ----------------
#define NN      8192
#define VV      8
#define PP      1024      // N / V
#define MM      2048
#define HE_DIM  1024
#define ST_DIM  512
#define D_OUT   256
#define K_HG    5
#define RADIUS  150.0f
#define TEMP    0.07f
#define EPSF    1e-12f

#define POOL_CHUNK 16
#define HE_NCH  (PP / POOL_CHUNK)   // 64
#define ST_NCH  (MM / POOL_CHUNK)   // 128
#define NHALF   16                  // 64-col halves per HE row (1024/64)

// grouped-GEMM block ranges
#define HE_TRI   36                 // 8x8 upper triangle
#define ST_TRI   136                // 16x16 upper triangle
#define NB_HE    (VV * HE_TRI)      // 288
#define NB_ST    ST_TRI             // 136
#define NB_PH    ((NN / 128) * (D_OUT / 128))   // 128
#define NB_PS    ((MM / 128) * (D_OUT / 128))   // 32
#define NB_ALL   (NB_HE + NB_ST + NB_PH + NB_PS) // 584 = 8 * 73

typedef __bf16 bf16x8 __attribute__((ext_vector_type(8)));
typedef float  f32x4  __attribute__((ext_vector_type(4)));
typedef unsigned short ushort_t;

typedef __attribute__((address_space(1))) void gvoid;
typedef __attribute__((address_space(3))) void svoid;
#define GLOAD16(g, l) __builtin_amdgcn_global_load_lds((gvoid*)(g), (svoid*)(l), 16, 0, 0)
#define FENCE() asm volatile("" ::: "memory")

// 5-slot descending insert (strict >; ascending-idx insertion order => ties keep smaller idx)
__device__ __forceinline__ void ins5(float s, int j, float* v, int* ic) {
    if (s > v[4]) {
        int p = 4;
        #pragma unroll
        for (int q = 4; q >= 1; --q) {
            if (s > v[q - 1]) { v[q] = v[q - 1]; ic[q] = ic[q - 1]; p = q - 1; }
            else break;
        }
        v[p] = s; ic[p] = j;
    }
}

// ---------------- fused: f32 -> (hi,lo) bf16 split + row L2 norm ----------------
__global__ __launch_bounds__(256) void prep_kernel(
    const float* __restrict__ F, const float* __restrict__ E,
    const float* __restrict__ Whe, const float* __restrict__ Wst,
    ushort_t* __restrict__ Fs, ushort_t* __restrict__ Es,
    ushort_t* __restrict__ Whes, ushort_t* __restrict__ Wsts,
    float* __restrict__ rnF, float* __restrict__ rnE)
{
    int b = blockIdx.x;
    const float* src; ushort_t* dst; float* rn; int K; long row;
    if (b < NN)                    { src = F;   dst = Fs;   rn = rnF;    K = HE_DIM; row = b; }
    else if (b < NN + MM)          { src = E;   dst = Es;   rn = rnE;    K = ST_DIM; row = b - NN; }
    else if (b < NN + MM + D_OUT)  { src = Whe; dst = Whes; rn = nullptr; K = HE_DIM; row = b - NN - MM; }
    else                           { src = Wst; dst = Wsts; rn = nullptr; K = ST_DIM; row = b - NN - MM - D_OUT; }
    const float4* srow = (const float4*)(src + row * (long)K);
    ushort_t* drow = dst + row * 2L * K;
    float s = 0.0f;
    for (int j4 = threadIdx.x; j4 < (K >> 2); j4 += 256) {
        float4 x = srow[j4];
        float xs[4] = {x.x, x.y, x.z, x.w};
        ushort_t hs[4], ls[4];
        #pragma unroll
        for (int t = 0; t < 4; ++t) {
            unsigned int bb = __float_as_uint(xs[t]);
            unsigned int hu = (bb + 0x7fffu + ((bb >> 16) & 1u)) >> 16;   // RNE bf16
            hs[t] = (ushort_t)hu;
            float hf = __uint_as_float(hu << 16);
            float l  = xs[t] - hf;                                        // exact
            unsigned int lb = __float_as_uint(l);
            ls[t] = (ushort_t)((lb + 0x7fffu + ((lb >> 16) & 1u)) >> 16);
            s += xs[t] * xs[t];
        }
        *(ushort4*)(drow + j4 * 4)     = make_ushort4(hs[0], hs[1], hs[2], hs[3]);
        *(ushort4*)(drow + K + j4 * 4) = make_ushort4(ls[0], ls[1], ls[2], ls[3]);
    }
    if (rn) {
        __shared__ float red[256];
        red[threadIdx.x] = s; __syncthreads();
        for (int o = 128; o > 0; o >>= 1) {
            if (threadIdx.x < o) red[threadIdx.x] += red[threadIdx.x + o];
            __syncthreads();
        }
        if (threadIdx.x == 0) rn[row] = 1.0f / fmaxf(sqrtf(red[0]), EPSF);
    }
}

// ---------------- merged region centroid + radius mask ----------------
__global__ __launch_bounds__(256) void centers_mask_kernel(
    const float* __restrict__ T, const float* __restrict__ S,
    int* __restrict__ mask, int* __restrict__ maskcnt)
{
    int v = blockIdx.x;
    float sx = 0.0f, sy = 0.0f;
    for (int i = threadIdx.x; i < PP; i += 256) {
        sx += T[(long)(v * PP + i) * 2 + 0];
        sy += T[(long)(v * PP + i) * 2 + 1];
    }
    __shared__ float rx[256], ry[256];
    __shared__ int   rc[256];
    rx[threadIdx.x] = sx; ry[threadIdx.x] = sy; __syncthreads();
    for (int o = 128; o > 0; o >>= 1) {
        if (threadIdx.x < o) { rx[threadIdx.x] += rx[threadIdx.x + o]; ry[threadIdx.x] += ry[threadIdx.x + o]; }
        __syncthreads();
    }
    float cx = rx[0] / (float)PP, cy = ry[0] / (float)PP;
    __syncthreads();
    int cnt = 0;
    for (int m = threadIdx.x; m < MM; m += 256) {
        float dx = cx - S[m * 2 + 0];
        float dy = cy - S[m * 2 + 1];
        int in = (sqrtf(dx * dx + dy * dy) < RADIUS) ? 1 : 0;
        mask[v * MM + m] = in;
        cnt += in;
    }
    rc[threadIdx.x] = cnt; __syncthreads();
    for (int o = 128; o > 0; o >>= 1) {
        if (threadIdx.x < o) rc[threadIdx.x] += rc[threadIdx.x + o];
        __syncthreads();
    }
    if (threadIdx.x == 0) maskcnt[v] = rc[0];
}

// ---------------- grouped split-bf16 MFMA GEMM ----------------
// op 0: HE Gram -> FUSED top-5 candidate emit (he_sim never materialized)
// op 1: ST Gram -> store + LDS-transposed coalesced mirror store
// op 2: projection -> plain store
__global__ __launch_bounds__(256) void gemm_grouped(
    const ushort_t* __restrict__ Fs, const ushort_t* __restrict__ Es,
    const ushort_t* __restrict__ Whes, const ushort_t* __restrict__ Wsts,
    float* __restrict__ he_cval, int* __restrict__ he_cidx,
    float* __restrict__ st_sim,
    float* __restrict__ Xw_he, float* __restrict__ Xw_st,
    const float* __restrict__ rnF, const float* __restrict__ rnE)
{
    // Balanced XCD map: XCD k owns region k's 36 HE tiles; round-robin rest.
    int bid = blockIdx.x;
    int xcd = bid & 7, j = bid >> 3;    // 584 = 8*73, bijective
    int id = (j < HE_TRI) ? (xcd * HE_TRI + j)
                          : (NB_HE + (j - HE_TRI) * 8 + xcd);

    const ushort_t *A, *B; float *C = nullptr;
    const float *rA = nullptr, *rB = nullptr;
    int K, Nn, bm, bn, op, zz = 0;
    if (id < NB_HE) {
        int z = id / HE_TRI, t = id - z * HE_TRI;
        int i = 0;
        while (t >= 8 - i) { t -= 8 - i; ++i; }
        bm = i * 128; bn = (i + t) * 128;
        A = B = Fs + (long)z * PP * 2 * HE_DIM;
        rA = rB = rnF + z * PP;
        K = HE_DIM; Nn = PP; op = 0; zz = z;
    } else if (id < NB_HE + NB_ST) {
        int t = id - NB_HE;
        int i = 0;
        while (t >= 16 - i) { t -= 16 - i; ++i; }
        bm = i * 128; bn = (i + t) * 128;
        A = B = Es; C = st_sim; rA = rB = rnE;
        K = ST_DIM; Nn = MM; op = 1;
    } else if (id < NB_HE + NB_ST + NB_PH) {
        int t = id - (NB_HE + NB_ST);
        bm = (t >> 1) * 128; bn = (t & 1) * 128;
        A = Fs; B = Whes; C = Xw_he;
        K = HE_DIM; Nn = D_OUT; op = 2;
    } else {
        int t = id - (NB_HE + NB_ST + NB_PH);
        bm = (t >> 1) * 128; bn = (t & 1) * 128;
        A = Es; B = Wsts; C = Xw_st;
        K = ST_DIM; Nn = D_OUT; op = 2;
    }

    // 2 buffers x 4 tiles (AH, AL, BH, BL) x 8 KB = 64 KB
    __shared__ ushort_t sm[2][4][4096];
    const int tid  = threadIdx.x;
    const int lane = tid & 63, wave = tid >> 6;
    const int wr = wave >> 1, wc = wave & 1;
    const int fr = lane & 15, fg = lane >> 4;

    const long lda = 2L * K;
    const int srow = wave * 16 + (lane >> 2);
    const int scol = (((lane & 3) ^ ((srow >> 1) & 3)) * 8);  // pre-swizzled src col

    auto STAGE = [&](int kk, int b) {
        const ushort_t* ga = A + (long)(bm + srow) * lda + kk + scol;
        const ushort_t* gb = B + (long)(bn + srow) * lda + kk + scol;
        char* AH = (char*)&sm[b][0][0] + wave * 1024;
        char* AL = (char*)&sm[b][1][0] + wave * 1024;
        char* BH = (char*)&sm[b][2][0] + wave * 1024;
        char* BL = (char*)&sm[b][3][0] + wave * 1024;
        GLOAD16(ga,                AH); GLOAD16(ga + 64 * lda,     AH + 4096);
        GLOAD16(ga + K,            AL); GLOAD16(ga + K + 64 * lda, AL + 4096);
        GLOAD16(gb,                BH); GLOAD16(gb + 64 * lda,     BH + 4096);
        GLOAD16(gb + K,            BL); GLOAD16(gb + K + 64 * lda, BL + 4096);
    };

    f32x4 acc[4][4] = {};
    STAGE(0, 0);
    int buf = 0;
    for (int kk = 0; kk < K; kk += 32) {
        if (kk + 32 < K) {
            STAGE(kk + 32, buf ^ 1);
            asm volatile("s_waitcnt vmcnt(8)" ::: "memory");
        } else {
            asm volatile("s_waitcnt vmcnt(0)" ::: "memory");
        }
        FENCE(); __builtin_amdgcn_s_barrier(); FENCE();
        bf16x8 ah[4], al[4], bh[4], bl[4];
        #pragma unroll
        for (int m = 0; m < 4; ++m) {
            int row = wr * 64 + m * 16 + fr;
            int ro = row * 64 + ((fg ^ ((row >> 1) & 3)) * 16);
            ah[m] = *(const bf16x8*)((const char*)&sm[buf][0][0] + ro);
            al[m] = *(const bf16x8*)((const char*)&sm[buf][1][0] + ro);
        }
        #pragma unroll
        for (int n = 0; n < 4; ++n) {
            int row = wc * 64 + n * 16 + fr;
            int ro = row * 64 + ((fg ^ ((row >> 1) & 3)) * 16);
            bh[n] = *(const bf16x8*)((const char*)&sm[buf][2][0] + ro);
            bl[n] = *(const bf16x8*)((const char*)&sm[buf][3][0] + ro);
        }
        #pragma unroll
        for (int m = 0; m < 4; ++m)
            #pragma unroll
            for (int n = 0; n < 4; ++n) {
                acc[m][n] = __builtin_amdgcn_mfma_f32_16x16x32_bf16(ah[m], bh[n], acc[m][n], 0, 0, 0);
                acc[m][n] = __builtin_amdgcn_mfma_f32_16x16x32_bf16(al[m], bh[n], acc[m][n], 0, 0, 0);
                acc[m][n] = __builtin_amdgcn_mfma_f32_16x16x32_bf16(ah[m], bl[n], acc[m][n], 0, 0, 0);
            }
        FENCE(); __builtin_amdgcn_s_barrier(); FENCE();
        buf ^= 1;
    }

    if (op == 0) {
        // ---- fused top-5 candidate emit for HE Gram (no C store) ----
        // DIRECT: rows of bm-block; this wave's 64-col half = (bn>>6)+wc.
        const int halfD = (bn >> 6) + wc;
        #pragma unroll
        for (int m = 0; m < 4; ++m) {
            #pragma unroll
            for (int r = 0; r < 4; ++r) {
                int grow = bm + wr * 64 + m * 16 + fg * 4 + r;
                float ra = rA[grow];
                float v0[5]; int ic[5];
                #pragma unroll
                for (int q = 0; q < 5; ++q) { v0[q] = -INFINITY; ic[q] = 0x7fffffff; }
                #pragma unroll
                for (int n = 0; n < 4; ++n) {
                    int col = bn + wc * 64 + n * 16 + fr;
                    ins5(acc[m][n][r] * ra * rB[col], col, v0, ic);
                }
                // merge across the 16 lanes of this fg-group (masks 1,2,4,8)
                #pragma unroll
                for (int t5 = 0; t5 < 5; ++t5) {
                    float bv = v0[0]; int bi = ic[0];
                    #pragma unroll
                    for (int mk = 1; mk <= 8; mk <<= 1) {
                        float ov = __shfl_xor(bv, mk, 64);
                        int   oi = __shfl_xor(bi, mk, 64);
                        if (ov > bv || (ov == bv && oi < bi)) { bv = ov; bi = oi; }
                    }
                    if (fr == 0) {
                        long slot = ((long)(zz * PP + grow) * NHALF + halfD) * 5 + t5;
                        he_cval[slot] = bv; he_cidx[slot] = bi;
                    }
                    if (v0[0] == bv && ic[0] == bi) {
                        #pragma unroll
                        for (int p = 0; p < 4; ++p) { v0[p] = v0[p + 1]; ic[p] = ic[p + 1]; }
                        v0[4] = -INFINITY; ic[4] = 0x7fffffff;
                    }
                }
            }
        }
        if (bn > bm) {
            // TRANSPOSED: rows of bn-block; this wave's 64-col half = (bm>>6)+wr.
            const int halfT = (bm >> 6) + wr;
            #pragma unroll
            for (int n = 0; n < 4; ++n) {
                int rowp = bn + wc * 64 + n * 16 + fr;
                float rb = rB[rowp];
                float v0[5]; int ic[5];
                #pragma unroll
                for (int q = 0; q < 5; ++q) { v0[q] = -INFINITY; ic[q] = 0x7fffffff; }
                #pragma unroll
                for (int m = 0; m < 4; ++m)
                    #pragma unroll
                    for (int r = 0; r < 4; ++r) {
                        int colp = bm + wr * 64 + m * 16 + fg * 4 + r;
                        ins5(acc[m][n][r] * rA[colp] * rb, colp, v0, ic);
                    }
                // merge across 4 lanes {fr, fr+16, fr+32, fr+48} (masks 16,32)
                #pragma unroll
                for (int t5 = 0; t5 < 5; ++t5) {
                    float bv = v0[0]; int bi = ic[0];
                    #pragma unroll
                    for (int mk = 16; mk <= 32; mk <<= 1) {
                        float ov = __shfl_xor(bv, mk, 64);
                        int   oi = __shfl_xor(bi, mk, 64);
                        if (ov > bv || (ov == bv && oi < bi)) { bv = ov; bi = oi; }
                    }
                    if (fg == 0) {
                        long slot = ((long)(zz * PP + rowp) * NHALF + halfT) * 5 + t5;
                        he_cval[slot] = bv; he_cidx[slot] = bi;
                    }
                    if (v0[0] == bv && ic[0] == bi) {
                        #pragma unroll
                        for (int p = 0; p < 4; ++p) { v0[p] = v0[p + 1]; ic[p] = ic[p + 1]; }
                        v0[4] = -INFINITY; ic[4] = 0x7fffffff;
                    }
                }
            }
        }
    } else {
        // ---- direct coalesced store ----
        #pragma unroll
        for (int m = 0; m < 4; ++m) {
            #pragma unroll
            for (int r = 0; r < 4; ++r) {
                int row = bm + wr * 64 + m * 16 + fg * 4 + r;
                float ra = rA ? rA[row] : 1.0f;
                #pragma unroll
                for (int n = 0; n < 4; ++n) {
                    int col = bn + wc * 64 + n * 16 + fr;
                    float rb = rB ? rB[col] : 1.0f;
                    C[(long)row * Nn + col] = acc[m][n][r] * ra * rb;
                }
            }
        }
        if (op == 1 && bn > bm) {
            // ---- mirror store via LDS transpose (coalesced) ----
            float* tbuf = (float*)&sm[0][0][0];   // 64x132 f32 = 33.8 KB
            #pragma unroll
            for (int h = 0; h < 2; ++h) {
                __syncthreads();
                if (wc == h) {
                    #pragma unroll
                    for (int m = 0; m < 4; ++m)
                        #pragma unroll
                        for (int r = 0; r < 4; ++r) {
                            int row = wr * 64 + m * 16 + fg * 4 + r;
                            float ra = rA[bm + row];
                            #pragma unroll
                            for (int n = 0; n < 4; ++n) {
                                int cloc = n * 16 + fr;           // 0..63 within half
                                float rb = rB[bn + h * 64 + cloc];
                                tbuf[cloc * 132 + row] = acc[m][n][r] * ra * rb;
                            }
                        }
                }
                __syncthreads();
                #pragma unroll
                for (int q = 0; q < 8; ++q) {
                    int fi = (q * 256 + tid) * 4;    // 0..8191
                    int rp = fi >> 7;                // transposed row 0..63
                    int cp = fi & 127;               // col 0..127 (step 4)
                    float4 val = { tbuf[rp * 132 + cp],     tbuf[rp * 132 + cp + 1],
                                   tbuf[rp * 132 + cp + 2], tbuf[rp * 132 + cp + 3] };
                    *(float4*)&C[(long)(bn + h * 64 + rp) * Nn + bm + cp] = val;
                }
            }
        }
    }
}

// ---------------- merged HE candidate-merge + ST masked top-5 (+ degree counts) ----------------
__global__ __launch_bounds__(64) void topk_kernel(
    const float* __restrict__ he_cval, const int* __restrict__ he_cidx,
    const float* __restrict__ st_sim, const int* __restrict__ mask,
    int* __restrict__ he_idx, int* __restrict__ st_idx,
    int* __restrict__ he_cnt, int* __restrict__ st_cnt)
{
    int gb = blockIdx.x;
    int lane = threadIdx.x;
    if (gb < NN) {
        // ---- HE: merge 80 candidates ----
        int z = gb >> 10;
        const float* cv = he_cval + (long)gb * (NHALF * 5);
        const int*   ci = he_cidx + (long)gb * (NHALF * 5);
        float v[2]; int ix[2];
        v[0] = cv[lane]; ix[0] = ci[lane];
        if (lane < NHALF * 5 - 64) { v[1] = cv[64 + lane]; ix[1] = ci[64 + lane]; }
        else { v[1] = -INFINITY; ix[1] = 0x7fffffff; }
        if (v[1] > v[0] || (v[1] == v[0] && ix[1] < ix[0])) {
            float tv = v[0]; v[0] = v[1]; v[1] = tv;
            int ti = ix[0]; ix[0] = ix[1]; ix[1] = ti;
        }
        int sel[K_HG];
        #pragma unroll
        for (int t5 = 0; t5 < K_HG; ++t5) {
            float bv = v[0]; int bi = ix[0];
            for (int o = 32; o > 0; o >>= 1) {
                float ov = __shfl_xor(bv, o, 64);
                int   oi = __shfl_xor(bi, o, 64);
                if (ov > bv || (ov == bv && oi < bi)) { bv = ov; bi = oi; }
            }
            if (lane == 0) { he_idx[(long)gb * K_HG + t5] = bi; sel[t5] = bi; }
            if (v[0] == bv && ix[0] == bi) {
                v[0] = v[1]; ix[0] = ix[1];
                v[1] = -INFINITY; ix[1] = 0x7fffffff;
            }
        }
        if (lane == 0) {
            #pragma unroll
            for (int t5 = 0; t5 < K_HG; ++t5) atomicAdd(&he_cnt[z * PP + sel[t5]], 1);
        }
        return;
    }
    // ---- ST: masked scan of st_sim row ----
    int g2 = gb - NN;
    int z = g2 >> 11, e = g2 & (MM - 1);
    const int* mk = mask + (long)z * MM;
    int* outIdx = st_idx + (long)g2 * K_HG;
    if (mk[e] == 0) {
        if (lane == 0) {
            #pragma unroll
            for (int r = 0; r < K_HG; ++r) outIdx[r] = -1;
        }
        return;
    }
    const float* row = st_sim + (long)e * MM;
    float v[K_HG]; int ix[K_HG];
    #pragma unroll
    for (int r = 0; r < K_HG; ++r) { v[r] = -INFINITY; ix[r] = 0x7fffffff; }
    for (int jj = lane; jj < MM; jj += 64) {
        if (mk[jj] == 0) continue;
        ins5(row[jj], jj, v, ix);
    }
    int sel[K_HG];
    #pragma unroll
    for (int r = 0; r < K_HG; ++r) {
        float bv = v[0]; int bi = ix[0];
        for (int o = 32; o > 0; o >>= 1) {
            float ov = __shfl_xor(bv, o, 64);
            int   oi = __shfl_xor(bi, o, 64);
            if (ov > bv || (ov == bv && oi < bi)) { bv = ov; bi = oi; }
        }
        if (lane == 0) { outIdx[r] = bi; sel[r] = bi; }
        if (v[0] == bv && ix[0] == bi) {
            #pragma unroll
            for (int p = 0; p < K_HG - 1; ++p) { v[p] = v[p + 1]; ix[p] = ix[p + 1]; }
            v[K_HG - 1] = -INFINITY; ix[K_HG - 1] = 0x7fffffff;
        }
    }
    if (lane == 0) {
        #pragma unroll
        for (int r = 0; r < K_HG; ++r) atomicAdd(&st_cnt[z * MM + sel[r]], 1);
    }
}

// ---------------- merged exclusive prefix scans (2 blocks) ----------------
template <int ELT>
__device__ void scan_impl(const int* __restrict__ cnt, int* __restrict__ off) {
    int tid = threadIdx.x;
    int base = tid * ELT;
    int loc[ELT]; int s = 0;
    #pragma unroll
    for (int i = 0; i < ELT; ++i) { loc[i] = s; s += cnt[base + i]; }
    __shared__ int red[1024];
    red[tid] = s; __syncthreads();
    for (int o = 1; o < 1024; o <<= 1) {
        int t = (tid >= o) ? red[tid - o] : 0;
        __syncthreads();
        red[tid] += t;
        __syncthreads();
    }
    int pre = red[tid] - s;
    #pragma unroll
    for (int i = 0; i < ELT; ++i) off[base + i] = pre + loc[i];
}

__global__ __launch_bounds__(1024) void scan_kernel(
    const int* __restrict__ he_cnt, int* __restrict__ he_off,
    const int* __restrict__ st_cnt, int* __restrict__ st_off) {
    if (blockIdx.x == 0) scan_impl<NN / 1024>(he_cnt, he_off);
    else                 scan_impl<(VV * MM) / 1024>(st_cnt, st_off);
}

// ---------------- merged per-edge value + CSR fill ----------------
__global__ __launch_bounds__(256) void edge_kernel(
    const int* __restrict__ he_idx, const int* __restrict__ st_idx,
    const float* __restrict__ Xw_he, const float* __restrict__ Xw_st,
    const int* __restrict__ he_cnt, const int* __restrict__ st_cnt,
    const int* __restrict__ he_off, const int* __restrict__ st_off,
    int* __restrict__ he_cur, int* __restrict__ st_cur,
    int* __restrict__ he_inv, int* __restrict__ st_inv,
    float* __restrict__ he_ev, float* __restrict__ st_ev)
{
    int b = blockIdx.x;
    const int *idx, *cnt, *off; const float* Xw;
    int *cur, *inv; float* ev;
    int ge, gbase, rowsPerZ; long xwBase;
    if (b < NN) {
        ge = b; int z = ge >> 10;
        idx = he_idx; Xw = Xw_he; cnt = he_cnt; off = he_off;
        cur = he_cur; inv = he_inv; ev = he_ev;
        rowsPerZ = PP; gbase = z * PP; xwBase = (long)z * PP;
    } else {
        ge = b - NN; int z = ge >> 11;
        idx = st_idx; Xw = Xw_st; cnt = st_cnt; off = st_off;
        cur = st_cur; inv = st_inv; ev = st_ev;
        rowsPerZ = MM; gbase = z * MM; xwBase = 0;
    }
    int mm[K_HG];
    #pragma unroll
    for (int k = 0; k < K_HG; ++k) mm[k] = idx[(long)ge * K_HG + k];
    if (mm[0] < 0) return;   // masked-out ST edge
    int d = threadIdx.x;
    float val = 0.0f;
    #pragma unroll
    for (int k = 0; k < K_HG; ++k) {
        int m = mm[k];
        if (m < 0 || m >= rowsPerZ) continue;
        float w = rsqrtf(fmaxf((float)cnt[gbase + m], EPSF));
        val += w * Xw[(xwBase + m) * D_OUT + d];
    }
    ev[(long)ge * D_OUT + d] = val * (1.0f / (float)K_HG);
    if (d < K_HG) {
        int m = mm[d];
        if (m >= 0 && m < rowsPerZ) {
            int g = gbase + m;
            int pos = atomicAdd(&cur[g], 1);
            inv[off[g] + pos] = ge;
        }
    }
}

// ---------------- node gather + Dv^-1/2 + GELU + partial pool ----------------
__global__ __launch_bounds__(256) void pool_gather_kernel(
    const float* __restrict__ he_ev, const float* __restrict__ st_ev,
    const int* __restrict__ he_off, const int* __restrict__ st_off,
    const int* __restrict__ he_cnt, const int* __restrict__ st_cnt,
    const int* __restrict__ he_inv, const int* __restrict__ st_inv,
    const int* __restrict__ mask,
    float* __restrict__ he_part, float* __restrict__ st_part)
{
    int blk = blockIdx.x;
    const float* ev; const int *off, *cnt, *inv, *msk = nullptr;
    float* partial; int gbase, i0;
    if (blk < VV * HE_NCH) {
        int z = blk >> 6, c = blk & (HE_NCH - 1);
        ev = he_ev; off = he_off; cnt = he_cnt; inv = he_inv;
        partial = he_part + (long)blk * D_OUT;
        gbase = z * PP; i0 = c * POOL_CHUNK;
    } else {
        int b2 = blk - VV * HE_NCH;
        int z = b2 >> 7, c = b2 & (ST_NCH - 1);
        ev = st_ev; off = st_off; cnt = st_cnt; inv = st_inv;
        msk = mask;
        partial = st_part + (long)b2 * D_OUT;
        gbase = z * MM; i0 = c * POOL_CHUNK;
    }
    int d = threadIdx.x;
    float s = 0.0f;
    for (int i = 0; i < POOL_CHUNK; ++i) {
        int g = gbase + i0 + i;
        if (msk && msk[g] == 0) continue;
        int cn = cnt[g], c0 = off[g];
        float a = 0.0f;
        for (int e = 0; e < cn; ++e)
            a += ev[(long)inv[c0 + e] * D_OUT + d];
        float w = rsqrtf(fmaxf((float)cn, EPSF));
        float x = w * a;
        s += 0.5f * x * (1.0f + erff(x * 0.70710678118654752f));   // exact GELU
    }
    partial[d] = s;
}

// ---------------- parallel partial reduce -> z vectors ----------------
__global__ __launch_bounds__(256) void pool_reduce_kernel(
    const float* __restrict__ he_part, const float* __restrict__ st_part,
    const int* __restrict__ maskcnt,
    float* __restrict__ z_he, float* __restrict__ z_st)
{
    int b = blockIdx.x, d = threadIdx.x;
    if (b < VV) {
        float s = 0.0f;
        for (int c = 0; c < HE_NCH; ++c) s += he_part[(long)(b * HE_NCH + c) * D_OUT + d];
        z_he[b * D_OUT + d] = s / (float)PP;
    } else {
        int v = b - VV;
        float s = 0.0f;
        for (int c = 0; c < ST_NCH; ++c) s += st_part[(long)(v * ST_NCH + c) * D_OUT + d];
        z_st[v * D_OUT + d] = s / (float)maskcnt[v];
    }
}

// ---------------- final contrastive loss (tiny) ----------------
__global__ __launch_bounds__(64) void final_kernel(const float* __restrict__ zhe,
                                                   const float* __restrict__ zst,
                                                   float* __restrict__ out) {
    __shared__ float he[VV][D_OUT];
    __shared__ float st[VV][D_OUT];
    __shared__ float lg[VV][VV];
    __shared__ float rn_he[VV], rn_st[VV];
    int t = threadIdx.x;
    for (int i = t; i < VV * D_OUT; i += 64) {
        he[i >> 8][i & 255] = zhe[i];
        st[i >> 8][i & 255] = zst[i];
    }
    __syncthreads();
    if (t < VV) {
        float s = 0.0f;
        for (int d2 = 0; d2 < D_OUT; ++d2) s += he[t][d2] * he[t][d2];
        rn_he[t] = 1.0f / fmaxf(sqrtf(s), EPSF);
    } else if (t < 2 * VV) {
        int v = t - VV; float s = 0.0f;
        for (int d2 = 0; d2 < D_OUT; ++d2) s += st[v][d2] * st[v][d2];
        rn_st[v] = 1.0f / fmaxf(sqrtf(s), EPSF);
    }
    __syncthreads();
    int v = t >> 3, w2 = t & 7;
    float dot = 0.0f;
    for (int d2 = 0; d2 < D_OUT; ++d2) dot += he[v][d2] * st[w2][d2];
    lg[v][w2] = dot * rn_he[v] * rn_st[w2] / TEMP;
    __syncthreads();
    if (t == 0) {
        float l1 = 0.0f, l2 = 0.0f;
        for (int i = 0; i < VV; ++i) {
            float mx = -1e30f;
            for (int jj = 0; jj < VV; ++jj) mx = fmaxf(mx, lg[i][jj]);
            float se = 0.0f;
            for (int jj = 0; jj < VV; ++jj) se += expf(lg[i][jj] - mx);
            l1 += lg[i][i] - (mx + logf(se));
            float mx2 = -1e30f;
            for (int jj = 0; jj < VV; ++jj) mx2 = fmaxf(mx2, lg[jj][i]);
            float se2 = 0.0f;
            for (int jj = 0; jj < VV; ++jj) se2 += expf(lg[jj][i] - mx2);
            l2 += lg[i][i] - (mx2 + logf(se2));
        }
        out[0] = 0.5f * (-(l1 / (float)VV) - (l2 / (float)VV));
    }
}

// ---------------- launch ----------------
extern "C" void kernel_launch(void* const* d_in, const int* in_sizes, int n_in,
                              void* d_out, int out_size, void* d_ws, size_t ws_size,
                              hipStream_t stream) {
    const float* F    = (const float*)d_in[0];
    const float* T    = (const float*)d_in[1];
    const float* E    = (const float*)d_in[3];
    const float* S    = (const float*)d_in[4];
    const float* W_he = (const float*)d_in[5];
    const float* W_st = (const float*)d_in[6];
    float* out = (float*)d_out;

    size_t off = 0;
    auto take = [&](size_t bytes) -> void* {
        void* p = (char*)d_ws + off;
        off += (bytes + 255) & ~(size_t)255;
        return p;
    };
    ushort_t* Fs    = (ushort_t*)take((size_t)NN * 2 * HE_DIM * 2);   // 33.5 MB
    ushort_t* Es    = (ushort_t*)take((size_t)MM * 2 * ST_DIM * 2);   // 4.2 MB
    ushort_t* Whes  = (ushort_t*)take((size_t)D_OUT * 2 * HE_DIM * 2);
    ushort_t* Wsts  = (ushort_t*)take((size_t)D_OUT * 2 * ST_DIM * 2);
    float* Xw_he    = (float*)take((size_t)NN * D_OUT * 4);           // 8 MB
    float* Xw_st    = (float*)take((size_t)MM * D_OUT * 4);           // 2 MB
    float* rnF      = (float*)take((size_t)NN * 4);
    float* rnE      = (float*)take((size_t)MM * 4);
    int*   mask     = (int*)  take((size_t)VV * MM * 4);
    int*   maskcnt  = (int*)  take((size_t)VV * 4);
    float* he_cval  = (float*)take((size_t)NN * NHALF * 5 * 4);       // 2.6 MB
    int*   he_cidx  = (int*)  take((size_t)NN * NHALF * 5 * 4);       // 2.6 MB
    float* st_sim   = (float*)take((size_t)MM * MM * 4);              // 16 MB
    int*   he_idx   = (int*)  take((size_t)NN * K_HG * 4);
    int*   st_idx   = (int*)  take((size_t)VV * MM * K_HG * 4);
    // zero-init region (one memset): counts + cursors
    size_t zero_beg = off;
    int*   he_cnt   = (int*)  take((size_t)NN * 4);
    int*   st_cnt   = (int*)  take((size_t)VV * MM * 4);
    int*   he_cur   = (int*)  take((size_t)NN * 4);
    int*   st_cur   = (int*)  take((size_t)VV * MM * 4);
    size_t zero_end = off;
    int*   he_off   = (int*)  take((size_t)NN * 4);
    int*   st_off   = (int*)  take((size_t)VV * MM * 4);
    int*   he_inv   = (int*)  take((size_t)NN * K_HG * 4);
    int*   st_inv   = (int*)  take((size_t)VV * MM * K_HG * 4);
    float* he_ev    = (float*)take((size_t)NN * D_OUT * 4);           // 8 MB
    float* st_ev    = (float*)take((size_t)VV * MM * D_OUT * 4);      // 16 MB
    float* he_part  = (float*)take((size_t)VV * HE_NCH * D_OUT * 4);
    float* st_part  = (float*)take((size_t)VV * ST_NCH * D_OUT * 4);
    float* z_he     = (float*)take((size_t)VV * D_OUT * 4);
    float* z_st     = (float*)take((size_t)VV * D_OUT * 4);

    hipMemsetAsync((char*)d_ws + zero_beg, 0, zero_end - zero_beg, stream);

    // split hi/lo + row norms
    prep_kernel<<<NN + MM + 2 * D_OUT, 256, 0, stream>>>(F, E, W_he, W_st,
                                                         Fs, Es, Whes, Wsts, rnF, rnE);
    // centroid + radius mask
    centers_mask_kernel<<<VV, 256, 0, stream>>>(T, S, mask, maskcnt);

    // all four GEMMs; HE Gram emits top-5 candidates in-epilogue (no he_sim)
    gemm_grouped<<<NB_ALL, 256, 0, stream>>>(Fs, Es, Whes, Wsts,
                                             he_cval, he_cidx, st_sim,
                                             Xw_he, Xw_st, rnF, rnE);

    // HE candidate merge + ST masked top-5 (+ degree counts), one launch
    topk_kernel<<<NN + VV * MM, 64, 0, stream>>>(he_cval, he_cidx, st_sim, mask,
                                                 he_idx, st_idx, he_cnt, st_cnt);
    // CSR offsets
    scan_kernel<<<2, 1024, 0, stream>>>(he_cnt, he_off, st_cnt, st_off);
    // per-edge values + CSR fill
    edge_kernel<<<NN + VV * MM, 256, 0, stream>>>(he_idx, st_idx, Xw_he, Xw_st,
                                                  he_cnt, st_cnt, he_off, st_off,
                                                  he_cur, st_cur, he_inv, st_inv,
                                                  he_ev, st_ev);
    // gather + gelu + partial pool
    pool_gather_kernel<<<VV * HE_NCH + VV * ST_NCH, 256, 0, stream>>>(
        he_ev, st_ev, he_off, st_off, he_cnt, st_cnt, he_inv, st_inv,
        mask, he_part, st_part);
    // reduce + loss
    pool_reduce_kernel<<<2 * VV, 256, 0, stream>>>(he_part, st_part, maskcnt, z_he, z_st);
    final_kernel<<<1, 64, 0, stream>>>(z_he, z_st, out);
}

// Round 9
// 223.764 us; speedup vs baseline: 1.3904x; 1.3904x over previous
//
#include <hip/hip_runtime.h>
#include <hip/hip_bf16.h>
#include <math.h>

// ---------------- problem constants ----------------
#define NN      8192
#define VV      8
#define PP      1024      // N / V
#define MM      2048
#define HE_DIM  1024
#define ST_DIM  512
#define D_OUT   256
#define K_HG    5
#define RADIUS  150.0f
#define TEMP    0.07f
#define EPSF    1e-12f

#define POOL_CHUNK 16
#define HE_NCH  (PP / POOL_CHUNK)   // 64
#define ST_NCH  (MM / POOL_CHUNK)   // 128

// grouped-GEMM block ranges
#define HE_TRI   36                 // 8x8 upper triangle
#define ST_TRI   136                // 16x16 upper triangle
#define NB_HE    (VV * HE_TRI)      // 288
#define NB_ST    ST_TRI             // 136
#define NB_PH    ((NN / 128) * (D_OUT / 128))   // 128
#define NB_PS    ((MM / 128) * (D_OUT / 128))   // 32
#define NB_ALL   (NB_HE + NB_ST + NB_PH + NB_PS) // 584 = 8 * 73

typedef __bf16 bf16x8 __attribute__((ext_vector_type(8)));
typedef float  f32x4  __attribute__((ext_vector_type(4)));
typedef unsigned short ushort_t;

typedef __attribute__((address_space(1))) void gvoid;
typedef __attribute__((address_space(3))) void svoid;
#define GLOAD16(g, l) __builtin_amdgcn_global_load_lds((gvoid*)(g), (svoid*)(l), 16, 0, 0)
#define FENCE() asm volatile("" ::: "memory")

__device__ __forceinline__ ushort_t f2bf(float x) {
    unsigned int b = __float_as_uint(x);
    return (ushort_t)((b + 0x7fffu + ((b >> 16) & 1u)) >> 16);   // RNE
}
__device__ __forceinline__ float bf2f(ushort_t h) {
    return __uint_as_float(((unsigned int)h) << 16);
}

// ---------------- fused: f32 -> (hi,lo) bf16 split + row L2 norm ----------------
__global__ __launch_bounds__(256) void prep_kernel(
    const float* __restrict__ F, const float* __restrict__ E,
    const float* __restrict__ Whe, const float* __restrict__ Wst,
    ushort_t* __restrict__ Fs, ushort_t* __restrict__ Es,
    ushort_t* __restrict__ Whes, ushort_t* __restrict__ Wsts,
    float* __restrict__ rnF, float* __restrict__ rnE)
{
    int b = blockIdx.x;
    const float* src; ushort_t* dst; float* rn; int K; long row;
    if (b < NN)                    { src = F;   dst = Fs;   rn = rnF;    K = HE_DIM; row = b; }
    else if (b < NN + MM)          { src = E;   dst = Es;   rn = rnE;    K = ST_DIM; row = b - NN; }
    else if (b < NN + MM + D_OUT)  { src = Whe; dst = Whes; rn = nullptr; K = HE_DIM; row = b - NN - MM; }
    else                           { src = Wst; dst = Wsts; rn = nullptr; K = ST_DIM; row = b - NN - MM - D_OUT; }
    const float4* srow = (const float4*)(src + row * (long)K);
    ushort_t* drow = dst + row * 2L * K;
    float s = 0.0f;
    for (int j4 = threadIdx.x; j4 < (K >> 2); j4 += 256) {
        float4 x = srow[j4];
        float xs[4] = {x.x, x.y, x.z, x.w};
        ushort_t hs[4], ls[4];
        #pragma unroll
        for (int t = 0; t < 4; ++t) {
            hs[t] = f2bf(xs[t]);
            float hf = bf2f(hs[t]);
            ls[t] = f2bf(xs[t] - hf);    // lo residual (exact subtraction)
            s += xs[t] * xs[t];
        }
        *(ushort4*)(drow + j4 * 4)     = make_ushort4(hs[0], hs[1], hs[2], hs[3]);
        *(ushort4*)(drow + K + j4 * 4) = make_ushort4(ls[0], ls[1], ls[2], ls[3]);
    }
    if (rn) {
        __shared__ float red[256];
        red[threadIdx.x] = s; __syncthreads();
        for (int o = 128; o > 0; o >>= 1) {
            if (threadIdx.x < o) red[threadIdx.x] += red[threadIdx.x + o];
            __syncthreads();
        }
        if (threadIdx.x == 0) rn[row] = 1.0f / fmaxf(sqrtf(red[0]), EPSF);
    }
}

// ---------------- merged region centroid + radius mask ----------------
__global__ __launch_bounds__(256) void centers_mask_kernel(
    const float* __restrict__ T, const float* __restrict__ S,
    int* __restrict__ mask, int* __restrict__ maskcnt)
{
    int v = blockIdx.x;
    float sx = 0.0f, sy = 0.0f;
    for (int i = threadIdx.x; i < PP; i += 256) {
        sx += T[(long)(v * PP + i) * 2 + 0];
        sy += T[(long)(v * PP + i) * 2 + 1];
    }
    __shared__ float rx[256], ry[256];
    __shared__ int   rc[256];
    rx[threadIdx.x] = sx; ry[threadIdx.x] = sy; __syncthreads();
    for (int o = 128; o > 0; o >>= 1) {
        if (threadIdx.x < o) { rx[threadIdx.x] += rx[threadIdx.x + o]; ry[threadIdx.x] += ry[threadIdx.x + o]; }
        __syncthreads();
    }
    float cx = rx[0] / (float)PP, cy = ry[0] / (float)PP;
    __syncthreads();
    int cnt = 0;
    for (int m = threadIdx.x; m < MM; m += 256) {
        float dx = cx - S[m * 2 + 0];
        float dy = cy - S[m * 2 + 1];
        int in = (sqrtf(dx * dx + dy * dy) < RADIUS) ? 1 : 0;
        mask[v * MM + m] = in;
        cnt += in;
    }
    rc[threadIdx.x] = cnt; __syncthreads();
    for (int o = 128; o > 0; o >>= 1) {
        if (threadIdx.x < o) rc[threadIdx.x] += rc[threadIdx.x + o];
        __syncthreads();
    }
    if (threadIdx.x == 0) maskcnt[v] = rc[0];
}

// ---------------- grouped split-bf16 MFMA GEMM ----------------
// 2-phase counted-vmcnt pipeline + XOR bank swizzle (R7, validated).
// NEW: symmetric mirror tiles stored via LDS transpose (coalesced, no scatter).
__global__ __launch_bounds__(256) void gemm_grouped(
    const ushort_t* __restrict__ Fs, const ushort_t* __restrict__ Es,
    const ushort_t* __restrict__ Whes, const ushort_t* __restrict__ Wsts,
    float* __restrict__ he_sim, float* __restrict__ st_sim,
    float* __restrict__ Xw_he, float* __restrict__ Xw_st,
    const float* __restrict__ rnF, const float* __restrict__ rnE)
{
    // Balanced XCD map: XCD k owns region k's 36 HE tiles; round-robin rest.
    int bid = blockIdx.x;
    int xcd = bid & 7, j = bid >> 3;    // 584 = 8*73, bijective
    int id = (j < HE_TRI) ? (xcd * HE_TRI + j)
                          : (NB_HE + (j - HE_TRI) * 8 + xcd);

    const ushort_t *A, *B; float *C;
    const float *rA = nullptr, *rB = nullptr;
    int K, Nn, bm, bn, sym;
    if (id < NB_HE) {
        int z = id / HE_TRI, t = id - z * HE_TRI;
        int i = 0;
        while (t >= 8 - i) { t -= 8 - i; ++i; }
        bm = i * 128; bn = (i + t) * 128;
        A = B = Fs + (long)z * PP * 2 * HE_DIM;
        C = he_sim + (long)z * PP * PP;
        rA = rB = rnF + z * PP;
        K = HE_DIM; Nn = PP; sym = 1;
    } else if (id < NB_HE + NB_ST) {
        int t = id - NB_HE;
        int i = 0;
        while (t >= 16 - i) { t -= 16 - i; ++i; }
        bm = i * 128; bn = (i + t) * 128;
        A = B = Es; C = st_sim; rA = rB = rnE;
        K = ST_DIM; Nn = MM; sym = 1;
    } else if (id < NB_HE + NB_ST + NB_PH) {
        int t = id - (NB_HE + NB_ST);
        bm = (t >> 1) * 128; bn = (t & 1) * 128;
        A = Fs; B = Whes; C = Xw_he;
        K = HE_DIM; Nn = D_OUT; sym = 0;
    } else {
        int t = id - (NB_HE + NB_ST + NB_PH);
        bm = (t >> 1) * 128; bn = (t & 1) * 128;
        A = Es; B = Wsts; C = Xw_st;
        K = ST_DIM; Nn = D_OUT; sym = 0;
    }

    // 2 buffers x 4 tiles (AH, AL, BH, BL) x 8 KB = 64 KB
    __shared__ ushort_t sm[2][4][4096];
    const int tid  = threadIdx.x;
    const int lane = tid & 63, wave = tid >> 6;
    const int wr = wave >> 1, wc = wave & 1;
    const int fr = lane & 15, fg = lane >> 4;

    const long lda = 2L * K;
    const int srow = wave * 16 + (lane >> 2);
    const int scol = (((lane & 3) ^ ((srow >> 1) & 3)) * 8);  // pre-swizzled src col

    auto STAGE = [&](int kk, int b) {
        const ushort_t* ga = A + (long)(bm + srow) * lda + kk + scol;
        const ushort_t* gb = B + (long)(bn + srow) * lda + kk + scol;
        char* AH = (char*)&sm[b][0][0] + wave * 1024;
        char* AL = (char*)&sm[b][1][0] + wave * 1024;
        char* BH = (char*)&sm[b][2][0] + wave * 1024;
        char* BL = (char*)&sm[b][3][0] + wave * 1024;
        GLOAD16(ga,                AH); GLOAD16(ga + 64 * lda,     AH + 4096);
        GLOAD16(ga + K,            AL); GLOAD16(ga + K + 64 * lda, AL + 4096);
        GLOAD16(gb,                BH); GLOAD16(gb + 64 * lda,     BH + 4096);
        GLOAD16(gb + K,            BL); GLOAD16(gb + K + 64 * lda, BL + 4096);
    };

    f32x4 acc[4][4] = {};
    STAGE(0, 0);
    int buf = 0;
    for (int kk = 0; kk < K; kk += 32) {
        if (kk + 32 < K) {
            STAGE(kk + 32, buf ^ 1);                      // prefetch next (8 loads)
            asm volatile("s_waitcnt vmcnt(8)" ::: "memory");  // only current buf must land
        } else {
            asm volatile("s_waitcnt vmcnt(0)" ::: "memory");
        }
        FENCE(); __builtin_amdgcn_s_barrier(); FENCE();
        bf16x8 ah[4], al[4], bh[4], bl[4];
        #pragma unroll
        for (int m = 0; m < 4; ++m) {
            int row = wr * 64 + m * 16 + fr;
            int ro = row * 64 + ((fg ^ ((row >> 1) & 3)) * 16);   // byte offset, swizzled
            ah[m] = *(const bf16x8*)((const char*)&sm[buf][0][0] + ro);
            al[m] = *(const bf16x8*)((const char*)&sm[buf][1][0] + ro);
        }
        #pragma unroll
        for (int n = 0; n < 4; ++n) {
            int row = wc * 64 + n * 16 + fr;
            int ro = row * 64 + ((fg ^ ((row >> 1) & 3)) * 16);
            bh[n] = *(const bf16x8*)((const char*)&sm[buf][2][0] + ro);
            bl[n] = *(const bf16x8*)((const char*)&sm[buf][3][0] + ro);
        }
        #pragma unroll
        for (int m = 0; m < 4; ++m)
            #pragma unroll
            for (int n = 0; n < 4; ++n) {
                acc[m][n] = __builtin_amdgcn_mfma_f32_16x16x32_bf16(ah[m], bh[n], acc[m][n], 0, 0, 0);
                acc[m][n] = __builtin_amdgcn_mfma_f32_16x16x32_bf16(al[m], bh[n], acc[m][n], 0, 0, 0);
                acc[m][n] = __builtin_amdgcn_mfma_f32_16x16x32_bf16(ah[m], bl[n], acc[m][n], 0, 0, 0);
            }
        FENCE(); __builtin_amdgcn_s_barrier(); FENCE();   // all waves done reading buf
        buf ^= 1;
    }

    // ---- direct coalesced store (all ops) ----
    #pragma unroll
    for (int m = 0; m < 4; ++m) {
        #pragma unroll
        for (int r = 0; r < 4; ++r) {
            int row = bm + wr * 64 + m * 16 + fg * 4 + r;
            float ra = rA ? rA[row] : 1.0f;
            #pragma unroll
            for (int n = 0; n < 4; ++n) {
                int col = bn + wc * 64 + n * 16 + fr;
                float rb = rB ? rB[col] : 1.0f;
                C[(long)row * Nn + col] = acc[m][n][r] * ra * rb;
            }
        }
    }
    if (sym && bn > bm) {
        // ---- mirror store via LDS transpose (coalesced; sm free after K-loop) ----
        float* tbuf = (float*)&sm[0][0][0];   // 64 x 132 f32 = 33.8 KB
        #pragma unroll
        for (int h = 0; h < 2; ++h) {
            __syncthreads();
            if (wc == h) {
                #pragma unroll
                for (int m = 0; m < 4; ++m)
                    #pragma unroll
                    for (int r = 0; r < 4; ++r) {
                        int row = wr * 64 + m * 16 + fg * 4 + r;
                        float ra = rA[bm + row];
                        #pragma unroll
                        for (int n = 0; n < 4; ++n) {
                            int cloc = n * 16 + fr;           // 0..63 within half
                            float rb = rB[bn + h * 64 + cloc];
                            tbuf[cloc * 132 + row] = acc[m][n][r] * ra * rb;
                        }
                    }
            }
            __syncthreads();
            #pragma unroll
            for (int q = 0; q < 8; ++q) {
                int fi = (q * 256 + tid) * 4;    // 0..8191
                int rp = fi >> 7;                // transposed row 0..63
                int cp = fi & 127;               // col 0..127 (step 4)
                float4 val = { tbuf[rp * 132 + cp],     tbuf[rp * 132 + cp + 1],
                               tbuf[rp * 132 + cp + 2], tbuf[rp * 132 + cp + 3] };
                *(float4*)&C[(long)(bn + h * 64 + rp) * Nn + bm + cp] = val;
            }
        }
    }
}

// ---------------- merged top-5 per row + degree counts ----------------
__global__ __launch_bounds__(64) void topk_kernel(
    const float* __restrict__ he_sim, const float* __restrict__ st_sim,
    const int* __restrict__ mask,
    int* __restrict__ he_idx, int* __restrict__ st_idx,
    int* __restrict__ he_cnt, int* __restrict__ st_cnt)
{
    int gb = blockIdx.x;
    const float* row; const int* mk = nullptr; int* outIdx; int* cntp; int n;
    if (gb < NN) {
        int z = gb >> 10, e = gb & (PP - 1);
        row = he_sim + (long)z * PP * PP + (long)e * PP;
        outIdx = he_idx + (long)gb * K_HG;
        cntp = he_cnt + z * PP;
        n = PP;
    } else {
        int g2 = gb - NN;
        int z = g2 >> 11, e = g2 & (MM - 1);
        mk = mask + (long)z * MM;
        row = st_sim + (long)e * MM;
        outIdx = st_idx + (long)g2 * K_HG;
        cntp = st_cnt + z * MM;
        n = MM;
        if (mk[e] == 0) {
            if (threadIdx.x == 0) {
                #pragma unroll
                for (int r = 0; r < K_HG; ++r) outIdx[r] = -1;
            }
            return;
        }
    }
    int lane = threadIdx.x;
    float v[K_HG]; int ix[K_HG];
    #pragma unroll
    for (int r = 0; r < K_HG; ++r) { v[r] = -INFINITY; ix[r] = 0x7fffffff; }
    for (int jj = lane; jj < n; jj += 64) {
        if (mk && mk[jj] == 0) continue;
        float s = row[jj];
        if (s > v[K_HG - 1]) {
            int p = K_HG - 1;
            #pragma unroll
            for (int q = K_HG - 1; q >= 1; --q) {
                if (s > v[q - 1]) { v[q] = v[q - 1]; ix[q] = ix[q - 1]; p = q - 1; }
                else break;
            }
            v[p] = s; ix[p] = jj;
        }
    }
    int sel[K_HG];
    #pragma unroll
    for (int r = 0; r < K_HG; ++r) {
        float bv = v[0]; int bi = ix[0];
        for (int o = 32; o > 0; o >>= 1) {
            float ov = __shfl_xor(bv, o, 64);
            int   oi = __shfl_xor(bi, o, 64);
            if (ov > bv || (ov == bv && oi < bi)) { bv = ov; bi = oi; }
        }
        if (lane == 0) { outIdx[r] = bi; sel[r] = bi; }
        if (v[0] == bv && ix[0] == bi) {
            #pragma unroll
            for (int p = 0; p < K_HG - 1; ++p) { v[p] = v[p + 1]; ix[p] = ix[p + 1]; }
            v[K_HG - 1] = -INFINITY; ix[K_HG - 1] = 0x7fffffff;
        }
    }
    if (lane == 0) {
        #pragma unroll
        for (int r = 0; r < K_HG; ++r) atomicAdd(&cntp[sel[r]], 1);
    }
}

// ---------------- merged exclusive prefix scans (2 blocks) ----------------
template <int ELT>
__device__ void scan_impl(const int* __restrict__ cnt, int* __restrict__ off) {
    int tid = threadIdx.x;
    int base = tid * ELT;
    int loc[ELT]; int s = 0;
    #pragma unroll
    for (int i = 0; i < ELT; ++i) { loc[i] = s; s += cnt[base + i]; }
    __shared__ int red[1024];
    red[tid] = s; __syncthreads();
    for (int o = 1; o < 1024; o <<= 1) {
        int t = (tid >= o) ? red[tid - o] : 0;
        __syncthreads();
        red[tid] += t;
        __syncthreads();
    }
    int pre = red[tid] - s;
    #pragma unroll
    for (int i = 0; i < ELT; ++i) off[base + i] = pre + loc[i];
}

__global__ __launch_bounds__(1024) void scan_kernel(
    const int* __restrict__ he_cnt, int* __restrict__ he_off,
    const int* __restrict__ st_cnt, int* __restrict__ st_off) {
    if (blockIdx.x == 0) scan_impl<NN / 1024>(he_cnt, he_off);
    else                 scan_impl<(VV * MM) / 1024>(st_cnt, st_off);
}

// ---------------- merged per-edge value (bf16 out) + CSR fill ----------------
__global__ __launch_bounds__(256) void edge_kernel(
    const int* __restrict__ he_idx, const int* __restrict__ st_idx,
    const float* __restrict__ Xw_he, const float* __restrict__ Xw_st,
    const int* __restrict__ he_cnt, const int* __restrict__ st_cnt,
    const int* __restrict__ he_off, const int* __restrict__ st_off,
    int* __restrict__ he_cur, int* __restrict__ st_cur,
    int* __restrict__ he_inv, int* __restrict__ st_inv,
    ushort_t* __restrict__ he_ev, ushort_t* __restrict__ st_ev)
{
    int b = blockIdx.x;
    const int *idx, *cnt, *off; const float* Xw;
    int *cur, *inv; ushort_t* ev;
    int ge, gbase, rowsPerZ; long xwBase;
    if (b < NN) {
        ge = b; int z = ge >> 10;
        idx = he_idx; Xw = Xw_he; cnt = he_cnt; off = he_off;
        cur = he_cur; inv = he_inv; ev = he_ev;
        rowsPerZ = PP; gbase = z * PP; xwBase = (long)z * PP;
    } else {
        ge = b - NN; int z = ge >> 11;
        idx = st_idx; Xw = Xw_st; cnt = st_cnt; off = st_off;
        cur = st_cur; inv = st_inv; ev = st_ev;
        rowsPerZ = MM; gbase = z * MM; xwBase = 0;
    }
    int mm[K_HG];
    #pragma unroll
    for (int k = 0; k < K_HG; ++k) mm[k] = idx[(long)ge * K_HG + k];
    if (mm[0] < 0) return;   // masked-out ST edge
    int d = threadIdx.x;
    float val = 0.0f;
    #pragma unroll
    for (int k = 0; k < K_HG; ++k) {
        int m = mm[k];
        if (m < 0 || m >= rowsPerZ) continue;
        float w = rsqrtf(fmaxf((float)cnt[gbase + m], EPSF));
        val += w * Xw[(xwBase + m) * D_OUT + d];
    }
    ev[(long)ge * D_OUT + d] = f2bf(val * (1.0f / (float)K_HG));
    if (d < K_HG) {
        int m = mm[d];
        if (m >= 0 && m < rowsPerZ) {
            int g = gbase + m;
            int pos = atomicAdd(&cur[g], 1);
            inv[off[g] + pos] = ge;
        }
    }
}

// ---------------- node gather + Dv^-1/2 + GELU + partial pool ----------------
__global__ __launch_bounds__(256) void pool_gather_kernel(
    const ushort_t* __restrict__ he_ev, const ushort_t* __restrict__ st_ev,
    const int* __restrict__ he_off, const int* __restrict__ st_off,
    const int* __restrict__ he_cnt, const int* __restrict__ st_cnt,
    const int* __restrict__ he_inv, const int* __restrict__ st_inv,
    const int* __restrict__ mask,
    float* __restrict__ he_part, float* __restrict__ st_part)
{
    int blk = blockIdx.x;
    const ushort_t* ev; const int *off, *cnt, *inv, *msk = nullptr;
    float* partial; int gbase, i0;
    if (blk < VV * HE_NCH) {
        int z = blk >> 6, c = blk & (HE_NCH - 1);
        ev = he_ev; off = he_off; cnt = he_cnt; inv = he_inv;
        partial = he_part + (long)blk * D_OUT;
        gbase = z * PP; i0 = c * POOL_CHUNK;
    } else {
        int b2 = blk - VV * HE_NCH;
        int z = b2 >> 7, c = b2 & (ST_NCH - 1);
        ev = st_ev; off = st_off; cnt = st_cnt; inv = st_inv;
        msk = mask;
        partial = st_part + (long)b2 * D_OUT;
        gbase = z * MM; i0 = c * POOL_CHUNK;
    }
    int d = threadIdx.x;
    float s = 0.0f;
    for (int i = 0; i < POOL_CHUNK; ++i) {
        int g = gbase + i0 + i;
        if (msk && msk[g] == 0) continue;
        int cn = cnt[g], c0 = off[g];
        float a = 0.0f;
        for (int e = 0; e < cn; ++e)
            a += bf2f(ev[(long)inv[c0 + e] * D_OUT + d]);
        float w = rsqrtf(fmaxf((float)cn, EPSF));
        float x = w * a;
        s += 0.5f * x * (1.0f + erff(x * 0.70710678118654752f));   // exact GELU
    }
    partial[d] = s;
}

// ---------------- parallel partial reduce -> z vectors ----------------
__global__ __launch_bounds__(256) void pool_reduce_kernel(
    const float* __restrict__ he_part, const float* __restrict__ st_part,
    const int* __restrict__ maskcnt,
    float* __restrict__ z_he, float* __restrict__ z_st)
{
    int b = blockIdx.x, d = threadIdx.x;
    if (b < VV) {
        float s = 0.0f;
        for (int c = 0; c < HE_NCH; ++c) s += he_part[(long)(b * HE_NCH + c) * D_OUT + d];
        z_he[b * D_OUT + d] = s / (float)PP;
    } else {
        int v = b - VV;
        float s = 0.0f;
        for (int c = 0; c < ST_NCH; ++c) s += st_part[(long)(v * ST_NCH + c) * D_OUT + d];
        z_st[v * D_OUT + d] = s / (float)maskcnt[v];
    }
}

// ---------------- final contrastive loss (tiny) ----------------
__global__ __launch_bounds__(64) void final_kernel(const float* __restrict__ zhe,
                                                   const float* __restrict__ zst,
                                                   float* __restrict__ out) {
    __shared__ float he[VV][D_OUT];
    __shared__ float st[VV][D_OUT];
    __shared__ float lg[VV][VV];
    __shared__ float rn_he[VV], rn_st[VV];
    int t = threadIdx.x;
    for (int i = t; i < VV * D_OUT; i += 64) {
        he[i >> 8][i & 255] = zhe[i];
        st[i >> 8][i & 255] = zst[i];
    }
    __syncthreads();
    if (t < VV) {
        float s = 0.0f;
        for (int d2 = 0; d2 < D_OUT; ++d2) s += he[t][d2] * he[t][d2];
        rn_he[t] = 1.0f / fmaxf(sqrtf(s), EPSF);
    } else if (t < 2 * VV) {
        int v = t - VV; float s = 0.0f;
        for (int d2 = 0; d2 < D_OUT; ++d2) s += st[v][d2] * st[v][d2];
        rn_st[v] = 1.0f / fmaxf(sqrtf(s), EPSF);
    }
    __syncthreads();
    int v = t >> 3, w2 = t & 7;
    float dot = 0.0f;
    for (int d2 = 0; d2 < D_OUT; ++d2) dot += he[v][d2] * st[w2][d2];
    lg[v][w2] = dot * rn_he[v] * rn_st[w2] / TEMP;
    __syncthreads();
    if (t == 0) {
        float l1 = 0.0f, l2 = 0.0f;
        for (int i = 0; i < VV; ++i) {
            float mx = -1e30f;
            for (int jj = 0; jj < VV; ++jj) mx = fmaxf(mx, lg[i][jj]);
            float se = 0.0f;
            for (int jj = 0; jj < VV; ++jj) se += expf(lg[i][jj] - mx);
            l1 += lg[i][i] - (mx + logf(se));
            float mx2 = -1e30f;
            for (int jj = 0; jj < VV; ++jj) mx2 = fmaxf(mx2, lg[jj][i]);
            float se2 = 0.0f;
            for (int jj = 0; jj < VV; ++jj) se2 += expf(lg[jj][i] - mx2);
            l2 += lg[i][i] - (mx2 + logf(se2));
        }
        out[0] = 0.5f * (-(l1 / (float)VV) - (l2 / (float)VV));
    }
}

// ---------------- launch ----------------
extern "C" void kernel_launch(void* const* d_in, const int* in_sizes, int n_in,
                              void* d_out, int out_size, void* d_ws, size_t ws_size,
                              hipStream_t stream) {
    const float* F    = (const float*)d_in[0];
    const float* T    = (const float*)d_in[1];
    const float* E    = (const float*)d_in[3];
    const float* S    = (const float*)d_in[4];
    const float* W_he = (const float*)d_in[5];
    const float* W_st = (const float*)d_in[6];
    float* out = (float*)d_out;

    size_t off = 0;
    auto take = [&](size_t bytes) -> void* {
        void* p = (char*)d_ws + off;
        off += (bytes + 255) & ~(size_t)255;
        return p;
    };
    ushort_t* Fs    = (ushort_t*)take((size_t)NN * 2 * HE_DIM * 2);   // 33.5 MB
    ushort_t* Es    = (ushort_t*)take((size_t)MM * 2 * ST_DIM * 2);   // 4.2 MB
    ushort_t* Whes  = (ushort_t*)take((size_t)D_OUT * 2 * HE_DIM * 2);
    ushort_t* Wsts  = (ushort_t*)take((size_t)D_OUT * 2 * ST_DIM * 2);
    float* Xw_he    = (float*)take((size_t)NN * D_OUT * 4);           // 8 MB
    float* Xw_st    = (float*)take((size_t)MM * D_OUT * 4);           // 2 MB
    float* rnF      = (float*)take((size_t)NN * 4);
    float* rnE      = (float*)take((size_t)MM * 4);
    int*   mask     = (int*)  take((size_t)VV * MM * 4);
    int*   maskcnt  = (int*)  take((size_t)VV * 4);
    float* he_sim   = (float*)take((size_t)VV * PP * PP * 4);         // 32 MB
    float* st_sim   = (float*)take((size_t)MM * MM * 4);              // 16 MB
    int*   he_idx   = (int*)  take((size_t)NN * K_HG * 4);
    int*   st_idx   = (int*)  take((size_t)VV * MM * K_HG * 4);
    // zero-init region (one memset): counts + cursors
    size_t zero_beg = off;
    int*   he_cnt   = (int*)  take((size_t)NN * 4);
    int*   st_cnt   = (int*)  take((size_t)VV * MM * 4);
    int*   he_cur   = (int*)  take((size_t)NN * 4);
    int*   st_cur   = (int*)  take((size_t)VV * MM * 4);
    size_t zero_end = off;
    int*   he_off   = (int*)  take((size_t)NN * 4);
    int*   st_off   = (int*)  take((size_t)VV * MM * 4);
    int*   he_inv   = (int*)  take((size_t)NN * K_HG * 4);
    int*   st_inv   = (int*)  take((size_t)VV * MM * K_HG * 4);
    ushort_t* he_ev = (ushort_t*)take((size_t)NN * D_OUT * 2);        // 4 MB (bf16)
    ushort_t* st_ev = (ushort_t*)take((size_t)VV * MM * D_OUT * 2);   // 8 MB (bf16)
    float* he_part  = (float*)take((size_t)VV * HE_NCH * D_OUT * 4);
    float* st_part  = (float*)take((size_t)VV * ST_NCH * D_OUT * 4);
    float* z_he     = (float*)take((size_t)VV * D_OUT * 4);
    float* z_st     = (float*)take((size_t)VV * D_OUT * 4);

    hipMemsetAsync((char*)d_ws + zero_beg, 0, zero_end - zero_beg, stream);

    // split hi/lo + row norms (one launch)
    prep_kernel<<<NN + MM + 2 * D_OUT, 256, 0, stream>>>(F, E, W_he, W_st,
                                                         Fs, Es, Whes, Wsts, rnF, rnE);
    // centroid + radius mask per region
    centers_mask_kernel<<<VV, 256, 0, stream>>>(T, S, mask, maskcnt);

    // all four GEMMs in one grouped launch (counted-vmcnt pipeline + swizzle
    // + coalesced LDS-transposed mirror stores)
    gemm_grouped<<<NB_ALL, 256, 0, stream>>>(Fs, Es, Whes, Wsts,
                                             he_sim, st_sim, Xw_he, Xw_st,
                                             rnF, rnE);

    // top-5 + degree counts (one launch)
    topk_kernel<<<NN + VV * MM, 64, 0, stream>>>(he_sim, st_sim, mask,
                                                 he_idx, st_idx, he_cnt, st_cnt);
    // CSR offsets (both sides, one launch)
    scan_kernel<<<2, 1024, 0, stream>>>(he_cnt, he_off, st_cnt, st_off);
    // per-edge values (bf16) + CSR fill (one launch)
    edge_kernel<<<NN + VV * MM, 256, 0, stream>>>(he_idx, st_idx, Xw_he, Xw_st,
                                                  he_cnt, st_cnt, he_off, st_off,
                                                  he_cur, st_cur, he_inv, st_inv,
                                                  he_ev, st_ev);
    // gather + gelu + partial pool (one launch)
    pool_gather_kernel<<<VV * HE_NCH + VV * ST_NCH, 256, 0, stream>>>(
        he_ev, st_ev, he_off, st_off, he_cnt, st_cnt, he_inv, st_inv,
        mask, he_part, st_part);
    // parallel partial reduce, then tiny loss
    pool_reduce_kernel<<<2 * VV, 256, 0, stream>>>(he_part, st_part, maskcnt, z_he, z_st);
    final_kernel<<<1, 64, 0, stream>>>(z_he, z_st, out);
}